// Round 3
// baseline (738.446 us; speedup 1.0000x reference)
//
#include <hip/hip_runtime.h>
#include <cstdint>
#include <cstddef>
#include <math.h>

#define T_TOK 32768
#define DIM   1024
#define DFF   256
#define NE    8
#define ROWS  (T_TOK * 2)       // 65536 token-expert rows
#define MAXROWS 66048           // ROWS + padding (<=8*63, rounded up)
#define MAXTILES (MAXROWS / 64) // 1032

typedef unsigned short u16;
typedef __attribute__((ext_vector_type(8))) short v8s;   // 8 bf16 (4 VGPR)
typedef __attribute__((ext_vector_type(4))) float v4f;   // MFMA acc

__device__ __forceinline__ u16 f2bf(float f) {
  union { float f; unsigned u; } v; v.f = f;
  return (u16)((v.u + 0x7FFFu + ((v.u >> 16) & 1u)) >> 16);  // RNE
}
__device__ __forceinline__ float bf2f(u16 b) {
  union { unsigned u; float f; } v; v.u = ((unsigned)b) << 16; return v.f;
}

// ---------------- ws layout (bytes) ----------------
#define WS_W13  ((size_t)0)                                   // 8*512*1024*2 = 8388608
#define WS_W2T  ((size_t)8388608)                             // 8*1024*256*2 = 4194304
#define WS_H    ((size_t)12582912)                             // 66048*256*2  = 33816576
#define WS_RTOK ((size_t)46399488)                             // 66048*4
#define WS_RWT  ((size_t)46663680)                             // 66048*4
#define WS_CNT  ((size_t)46927872)                             // 8*4 (pad to 32)
#define WS_CUR  ((size_t)46927904)                             // 8*4 (pad to 32)
#define WS_OFF  ((size_t)46927936)                             // 9*4 (pad to 64)
#define WS_SEL  ((size_t)46928000)                             // 65536*4
#define WS_WTS  ((size_t)47190144)                             // 65536*4

// ============ weight packing: w1/w3 -> W13p[e][n=512][k=1024] bf16 ============
// n mapping: for pair j (0..255): w = j/32, i = j%32 -> w1 col at n=64w+i, w3 at n=64w+32+i
__global__ __launch_bounds__(256) void k_pack13(const float* __restrict__ w1,
                                                const float* __restrict__ w3,
                                                u16* __restrict__ W13p) {
  __shared__ float s1[32][33];
  __shared__ float s3[32][33];
  int e = blockIdx.z, k0 = blockIdx.x * 32, j0w = blockIdx.y; // j0 = j0w*32
  int tx = threadIdx.x, ty = threadIdx.y;
  size_t wbase = (size_t)e * DIM * DFF;
#pragma unroll
  for (int r = 0; r < 4; ++r) {
    int kl = ty + 8 * r;
    size_t src = wbase + (size_t)(k0 + kl) * DFF + j0w * 32 + tx;
    s1[kl][tx] = w1[src];
    s3[kl][tx] = w3[src];
  }
  __syncthreads();
  size_t obase = (size_t)e * 512 * 1024;
#pragma unroll
  for (int r = 0; r < 4; ++r) {
    int jl = ty + 8 * r;
    int n1 = 64 * j0w + jl;
    W13p[obase + (size_t)n1 * 1024 + k0 + tx]        = f2bf(s1[tx][jl]);
    W13p[obase + (size_t)(n1 + 32) * 1024 + k0 + tx] = f2bf(s3[tx][jl]);
  }
}

// ============ w2 [e][k=256][n=1024] -> W2t[e][n=1024][k=256] bf16 ============
__global__ __launch_bounds__(256) void k_pack2(const float* __restrict__ w2,
                                               u16* __restrict__ W2t) {
  __shared__ float s[32][33];
  int e = blockIdx.z, k0 = blockIdx.x * 32, n0 = blockIdx.y * 32;
  int tx = threadIdx.x, ty = threadIdx.y;
#pragma unroll
  for (int r = 0; r < 4; ++r) {
    int kl = ty + 8 * r;
    s[kl][tx] = w2[(size_t)e * DFF * DIM + (size_t)(k0 + kl) * DIM + n0 + tx];
  }
  __syncthreads();
#pragma unroll
  for (int r = 0; r < 4; ++r) {
    int nl = ty + 8 * r;
    W2t[(size_t)e * DIM * DFF + (size_t)(n0 + nl) * DFF + k0 + tx] = f2bf(s[tx][nl]);
  }
}

// ============ router: np/BLAS-order fp32 logits ============
// One thread per (token, expert): logit = sequential fp32 fmaf over k=0..1023,
// exactly the order an sgemm micro-kernel uses (one accumulator per C element,
// k ascending, FMA; K-blocking round-trips through fp32 C which is identity).
// Softmax is per-token monotone -> top-2 selection directly on logits with
// strict-> lowest-index tie-break (jax top_k semantics).
__global__ __launch_bounds__(256) void k_router(const float* __restrict__ x,
                                                const float* __restrict__ rw,
                                                int* __restrict__ sel,
                                                float* __restrict__ wts,
                                                int* __restrict__ cnt) {
  __shared__ __align__(16) float s_rw[NE * DIM];  // 32 KB
  __shared__ float s_lg[256];
  __shared__ int s_cnt[NE];
  int tid = threadIdx.x;
  if (tid < NE) s_cnt[tid] = 0;
  {
    const float4* rw4 = (const float4*)rw;
    float4* s4 = (float4*)s_rw;
#pragma unroll
    for (int i = 0; i < 8; ++i) s4[tid + i * 256] = rw4[tid + i * 256];
  }
  __syncthreads();
  int g = blockIdx.x * 256 + tid;  // (t,e) pair; 32 tokens per block
  int t = g >> 3, e = g & 7;
  const float* xr = x + (size_t)t * DIM;
  const float* wr = s_rw + e * DIM;
  float acc = 0.0f;
#pragma unroll 8
  for (int k = 0; k < DIM; ++k) acc = fmaf(xr[k], wr[k], acc);  // strict sequential
  s_lg[tid] = acc;
  __syncthreads();
  if ((tid & 7) == 0) {
    const float* lg = s_lg + tid;
    int b0 = 0; float v0 = lg[0];
#pragma unroll
    for (int ee = 1; ee < NE; ++ee) if (lg[ee] > v0) { v0 = lg[ee]; b0 = ee; }
    int b1 = -1; float v1 = -1e30f;
#pragma unroll
    for (int ee = 0; ee < NE; ++ee) if (ee != b0 && lg[ee] > v1) { v1 = lg[ee]; b1 = ee; }
    float w0 = 1.0f / (1.0f + expf(v1 - v0));  // v1<=v0, safe
    sel[2 * t] = b0; sel[2 * t + 1] = b1;
    wts[2 * t] = w0; wts[2 * t + 1] = 1.0f - w0;
    atomicAdd(&s_cnt[b0], 1); atomicAdd(&s_cnt[b1], 1);
  }
  __syncthreads();
  if (tid < NE && s_cnt[tid]) atomicAdd(&cnt[tid], s_cnt[tid]);
}

// ============ scan: padded (x64) exclusive offsets ============
__global__ void k_scan(const int* __restrict__ cnt, int* __restrict__ offs) {
  if (threadIdx.x == 0 && blockIdx.x == 0) {
    int o = 0;
#pragma unroll
    for (int e = 0; e < NE; ++e) { offs[e] = o; o += (cnt[e] + 63) & ~63; }
    offs[NE] = o;
  }
}

// ============ scatter: build expert-sorted row lists ============
__global__ __launch_bounds__(256) void k_scatter(const int* __restrict__ sel,
                                                 const float* __restrict__ wts,
                                                 const int* __restrict__ offs,
                                                 int* __restrict__ cursor,
                                                 int* __restrict__ rtok,
                                                 float* __restrict__ rwt) {
  __shared__ int s_cnt[NE], s_base[NE];
  int tid = threadIdx.x;
  if (tid < NE) s_cnt[tid] = 0;
  __syncthreads();
  int g = blockIdx.x * 256 + tid;          // 0..65535 (token*2+slot)
  int e = sel[g];
  int lpos = atomicAdd(&s_cnt[e], 1);
  __syncthreads();
  if (tid < NE) s_base[tid] = s_cnt[tid] ? atomicAdd(&cursor[tid], s_cnt[tid]) : 0;
  __syncthreads();
  int row = offs[e] + s_base[e] + lpos;
  rtok[row] = g >> 1;
  rwt[row] = wts[g];
}

// ============ GEMM1 + SwiGLU: h[row][256] = silu(x@w1) * (x@w3), bf16 ============
__global__ __launch_bounds__(512, 4) void k_gemm1(const float* __restrict__ x,
                                                  const u16* __restrict__ W13p,
                                                  const int* __restrict__ rtok,
                                                  const int* __restrict__ offs,
                                                  u16* __restrict__ h) {
  __shared__ __align__(16) u16 A_s[64][40];   // 5 KB, pad 40 to break bank stride
  __shared__ __align__(16) u16 B_s[512][40];  // 40 KB
  int row0 = blockIdx.x * 64;
  if (row0 >= offs[NE]) return;
  int e = 0;
  while (row0 >= offs[e + 1]) ++e;
  int tid = threadIdx.x;
  int ar = tid >> 3, ac = (tid & 7) * 4;
  const float* xrow = x + (size_t)rtok[row0 + ar] * DIM;
  const u16* Bb = W13p + (size_t)e * 512 * 1024;
  int wv = tid >> 6, lane = tid & 63;
  int lr = lane & 15, q = lane >> 4;
  v4f acc[4][4] = {};
  for (int k0 = 0; k0 < DIM; k0 += 32) {
    float4 xv = *(const float4*)(xrow + k0 + ac);
    ushort4 a4;
    a4.x = f2bf(xv.x); a4.y = f2bf(xv.y); a4.z = f2bf(xv.z); a4.w = f2bf(xv.w);
    *(ushort4*)(&A_s[ar][ac]) = a4;
#pragma unroll
    for (int qq = 0; qq < 4; ++qq) {
      int id = qq * 512 + tid;
      int n = id >> 2, c8 = (id & 3) * 8;
      *(uint4*)(&B_s[n][c8]) = *(const uint4*)(Bb + (size_t)n * 1024 + k0 + c8);
    }
    __syncthreads();
    v8s a[4], b[4];
#pragma unroll
    for (int mt = 0; mt < 4; ++mt) a[mt] = *(const v8s*)(&A_s[16 * mt + lr][q * 8]);
#pragma unroll
    for (int nt = 0; nt < 4; ++nt) b[nt] = *(const v8s*)(&B_s[64 * wv + 16 * nt + lr][q * 8]);
#pragma unroll
    for (int mt = 0; mt < 4; ++mt)
#pragma unroll
      for (int nt = 0; nt < 4; ++nt)
        acc[mt][nt] = __builtin_amdgcn_mfma_f32_16x16x32_bf16(a[mt], b[nt], acc[mt][nt], 0, 0, 0);
    __syncthreads();
  }
  // SwiGLU epilogue: wave wv holds pairs j = 32*wv + 16*nt + lr (nt=0,1), partner at nt+2
#pragma unroll
  for (int mt = 0; mt < 4; ++mt)
#pragma unroll
    for (int nt = 0; nt < 2; ++nt)
#pragma unroll
      for (int r = 0; r < 4; ++r) {
        float x1 = bf2f(f2bf(acc[mt][nt][r]));      // match ref bf16 rounding
        float x3 = bf2f(f2bf(acc[mt][nt + 2][r]));
        float hv = x1 * x3 / (1.0f + __expf(-x1));  // silu(x1)*x3
        int row = row0 + 16 * mt + q * 4 + r;
        int col = 32 * wv + 16 * nt + lr;
        h[(size_t)row * DFF + col] = f2bf(hv);
      }
}

// ============ GEMM2 + weighted scatter-add: out[tok] += (h@w2) * wt ============
__global__ __launch_bounds__(512, 4) void k_gemm2(const u16* __restrict__ h,
                                                  const u16* __restrict__ W2t,
                                                  const int* __restrict__ rtok,
                                                  const float* __restrict__ rwt,
                                                  const int* __restrict__ offs,
                                                  float* __restrict__ out) {
  __shared__ __align__(16) u16 A_s[64][40];
  __shared__ __align__(16) u16 B_s[512][40];
  __shared__ int s_tok[64];
  __shared__ float s_wt[64];
  int row0 = blockIdx.x * 64;
  if (row0 >= offs[NE]) return;
  int e = 0;
  while (row0 >= offs[e + 1]) ++e;
  int nb = blockIdx.y;
  int tid = threadIdx.x;
  if (tid < 64) { s_tok[tid] = rtok[row0 + tid]; s_wt[tid] = rwt[row0 + tid]; }
  int ar = tid >> 3, ac = (tid & 7) * 4;
  const u16* hrow = h + (size_t)(row0 + ar) * DFF;
  const u16* Bb = W2t + (size_t)e * DIM * DFF + (size_t)nb * 512 * DFF;
  int wv = tid >> 6, lane = tid & 63;
  int lr = lane & 15, q = lane >> 4;
  v4f acc[4][4] = {};
  for (int k0 = 0; k0 < DFF; k0 += 32) {
    *(ushort4*)(&A_s[ar][ac]) = *(const ushort4*)(hrow + k0 + ac);
#pragma unroll
    for (int qq = 0; qq < 4; ++qq) {
      int id = qq * 512 + tid;
      int n = id >> 2, c8 = (id & 3) * 8;
      *(uint4*)(&B_s[n][c8]) = *(const uint4*)(Bb + (size_t)n * DFF + k0 + c8);
    }
    __syncthreads();
    v8s a[4], b[4];
#pragma unroll
    for (int mt = 0; mt < 4; ++mt) a[mt] = *(const v8s*)(&A_s[16 * mt + lr][q * 8]);
#pragma unroll
    for (int nt = 0; nt < 4; ++nt) b[nt] = *(const v8s*)(&B_s[64 * wv + 16 * nt + lr][q * 8]);
#pragma unroll
    for (int mt = 0; mt < 4; ++mt)
#pragma unroll
      for (int nt = 0; nt < 4; ++nt)
        acc[mt][nt] = __builtin_amdgcn_mfma_f32_16x16x32_bf16(a[mt], b[nt], acc[mt][nt], 0, 0, 0);
    __syncthreads();
  }
#pragma unroll
  for (int mt = 0; mt < 4; ++mt)
#pragma unroll
    for (int nt = 0; nt < 4; ++nt) {
      int col = nb * 512 + 64 * wv + 16 * nt + lr;
#pragma unroll
      for (int r = 0; r < 4; ++r) {
        int m = 16 * mt + q * 4 + r;
        float val = bf2f(f2bf(acc[mt][nt][r])) * s_wt[m];  // ref rounds expert_out to bf16
        atomicAdd(out + (size_t)s_tok[m] * DIM + col, val);
      }
    }
}

extern "C" void kernel_launch(void* const* d_in, const int* in_sizes, int n_in,
                              void* d_out, int out_size, void* d_ws, size_t ws_size,
                              hipStream_t stream) {
  (void)in_sizes; (void)n_in; (void)ws_size;
  const float* x  = (const float*)d_in[0];
  const float* rw = (const float*)d_in[1];
  const float* w1 = (const float*)d_in[2];
  const float* w2 = (const float*)d_in[3];
  const float* w3 = (const float*)d_in[4];
  float* out = (float*)d_out;
  char* ws = (char*)d_ws;
  u16*   W13p = (u16*)(ws + WS_W13);
  u16*   W2t  = (u16*)(ws + WS_W2T);
  u16*   hbuf = (u16*)(ws + WS_H);
  int*   rtok = (int*)(ws + WS_RTOK);
  float* rwt  = (float*)(ws + WS_RWT);
  int*   cnt  = (int*)(ws + WS_CNT);
  int*   cur  = (int*)(ws + WS_CUR);
  int*   offs = (int*)(ws + WS_OFF);
  int*   sel  = (int*)(ws + WS_SEL);
  float* wts  = (float*)(ws + WS_WTS);

  hipMemsetAsync(d_out, 0, (size_t)out_size * sizeof(float), stream);
  hipMemsetAsync(ws + WS_RTOK, 0, (WS_OFF + 64) - WS_RTOK, stream);  // rtok,rwt,cnt,cur,offs

  k_pack13<<<dim3(32, 8, 8), dim3(32, 8), 0, stream>>>(w1, w3, W13p);
  k_pack2 <<<dim3(8, 32, 8), dim3(32, 8), 0, stream>>>(w2, W2t);
  k_router<<<dim3(T_TOK * NE / 256), dim3(256), 0, stream>>>(x, rw, sel, wts, cnt);
  k_scan  <<<dim3(1), dim3(64), 0, stream>>>(cnt, offs);
  k_scatter<<<dim3(ROWS / 256), dim3(256), 0, stream>>>(sel, wts, offs, cur, rtok, rwt);
  k_gemm1 <<<dim3(MAXTILES), dim3(512), 0, stream>>>(x, W13p, rtok, offs, hbuf);
  k_gemm2 <<<dim3(MAXTILES, 2), dim3(512), 0, stream>>>(hbuf, W2t, rtok, rwt, offs, out);
}

// Round 4
// 601.853 us; speedup vs baseline: 1.2270x; 1.2270x over previous
//
#include <hip/hip_runtime.h>
#include <cstdint>
#include <cstddef>
#include <math.h>

#define T_TOK 32768
#define DIM   1024
#define DFF   256
#define NE    8
#define NB    16                 // (expert, slot) bins
#define ROWS  (T_TOK * 2)        // 65536 token-expert rows
#define MAXROWS 66560            // ROWS + 16*63 pad, rounded to x64
#define MAXTILES (MAXROWS / 64)  // 1040

typedef unsigned short u16;
typedef __attribute__((ext_vector_type(8))) short v8s;   // 8 bf16 (4 VGPR)
typedef __attribute__((ext_vector_type(4))) float v4f;   // MFMA acc

__device__ __forceinline__ u16 f2bf(float f) {
  union { float f; unsigned u; } v; v.f = f;
  return (u16)((v.u + 0x7FFFu + ((v.u >> 16) & 1u)) >> 16);  // RNE
}
__device__ __forceinline__ float bf2f(u16 b) {
  union { unsigned u; float f; } v; v.u = ((unsigned)b) << 16; return v.f;
}

// ---------------- ws layout (bytes) ----------------
#define WS_W13  ((size_t)0)            // 8*512*1024*2  = 8388608
#define WS_W2T  ((size_t)8388608)      // 8*1024*256*2  = 4194304
#define WS_H    ((size_t)12582912)     // 66560*256*2   = 34078720
#define WS_RTOK ((size_t)46661632)     // 66560*4       = 266240
#define WS_RWT  ((size_t)46927872)     // 66560*4       = 266240
#define WS_CNT  ((size_t)47194112)     // 16*4 pad 64
#define WS_CUR  ((size_t)47194176)     // 16*4 pad 64
#define WS_OFF  ((size_t)47194240)     // 17*4 pad 128
#define WS_SEL  ((size_t)47194368)     // 65536*4
#define WS_WTS  ((size_t)47456512)     // 65536*4  -> total 47718656

// ============ weight packing: w1/w3 -> W13p[e][n=512][k=1024] bf16 ============
__global__ __launch_bounds__(256) void k_pack13(const float* __restrict__ w1,
                                                const float* __restrict__ w3,
                                                u16* __restrict__ W13p) {
  __shared__ float s1[32][33];
  __shared__ float s3[32][33];
  int e = blockIdx.z, k0 = blockIdx.x * 32, j0w = blockIdx.y;
  int tx = threadIdx.x, ty = threadIdx.y;
  size_t wbase = (size_t)e * DIM * DFF;
#pragma unroll
  for (int r = 0; r < 4; ++r) {
    int kl = ty + 8 * r;
    size_t src = wbase + (size_t)(k0 + kl) * DFF + j0w * 32 + tx;
    s1[kl][tx] = w1[src];
    s3[kl][tx] = w3[src];
  }
  __syncthreads();
  size_t obase = (size_t)e * 512 * 1024;
#pragma unroll
  for (int r = 0; r < 4; ++r) {
    int jl = ty + 8 * r;
    int n1 = 64 * j0w + jl;
    W13p[obase + (size_t)n1 * 1024 + k0 + tx]        = f2bf(s1[tx][jl]);
    W13p[obase + (size_t)(n1 + 32) * 1024 + k0 + tx] = f2bf(s3[tx][jl]);
  }
}

// ============ w2 [e][k=256][n=1024] -> W2t[e][n=1024][k=256] bf16 ============
__global__ __launch_bounds__(256) void k_pack2(const float* __restrict__ w2,
                                               u16* __restrict__ W2t) {
  __shared__ float s[32][33];
  int e = blockIdx.z, k0 = blockIdx.x * 32, n0 = blockIdx.y * 32;
  int tx = threadIdx.x, ty = threadIdx.y;
#pragma unroll
  for (int r = 0; r < 4; ++r) {
    int kl = ty + 8 * r;
    s[kl][tx] = w2[(size_t)e * DFF * DIM + (size_t)(k0 + kl) * DIM + n0 + tx];
  }
  __syncthreads();
#pragma unroll
  for (int r = 0; r < 4; ++r) {
    int nl = ty + 8 * r;
    W2t[(size_t)e * DIM * DFF + (size_t)(n0 + nl) * DFF + k0 + tx] = f2bf(s[tx][nl]);
  }
}

// ============ router: np-order fp32 logits, LDS-staged (coalesced) ============
// Per (t,e): sequential fmaf over k=0..1023 — bit-identical order/values to the
// round-3 passing version; only the memory path (LDS staging) changed.
__global__ __launch_bounds__(256) void k_router(const float* __restrict__ x,
                                                const float* __restrict__ rw,
                                                int* __restrict__ sel,
                                                float* __restrict__ wts,
                                                int* __restrict__ cnt) {
  __shared__ __align__(16) float s_rw[NE][1028];  // pad: banks spread by 4*e
  __shared__ __align__(16) float s_x[32][132];    // pad: banks spread by 4*t
  __shared__ float s_lg[256];
  __shared__ int s_cnt[NB];
  int tid = threadIdx.x;
  if (tid < NB) s_cnt[tid] = 0;
  {
    const float4* rw4 = (const float4*)rw;
#pragma unroll
    for (int r = 0; r < 8; ++r)
      *(float4*)(&s_rw[r][tid * 4]) = rw4[r * 256 + tid];
  }
  int tl = tid >> 3, e = tid & 7;
  float acc = 0.0f;
  const float4* x4 = (const float4*)x;
  for (int c = 0; c < 8; ++c) {          // 8 chunks of 128 k
    __syncthreads();
#pragma unroll
    for (int j = 0; j < 4; ++j) {
      int slot = j * 256 + tid;          // 1024 float4 slots
      int t = slot >> 5, kk = (slot & 31) * 4;
      *(float4*)(&s_x[t][kk]) = x4[((size_t)blockIdx.x * 32 + t) * 256 + c * 32 + (slot & 31)];
    }
    __syncthreads();
    const float* xp = &s_x[tl][0];
    const float* wp = &s_rw[e][c * 128];
#pragma unroll 16
    for (int k = 0; k < 128; ++k) acc = fmaf(xp[k], wp[k], acc);  // strict sequential
  }
  s_lg[tid] = acc;
  __syncthreads();
  if ((tid & 7) == 0) {
    int t = blockIdx.x * 32 + tl;
    const float* lg = s_lg + tid;
    int b0 = 0; float v0 = lg[0];
#pragma unroll
    for (int ee = 1; ee < NE; ++ee) if (lg[ee] > v0) { v0 = lg[ee]; b0 = ee; }
    int b1 = -1; float v1 = -1e30f;
#pragma unroll
    for (int ee = 0; ee < NE; ++ee) if (ee != b0 && lg[ee] > v1) { v1 = lg[ee]; b1 = ee; }
    float w0 = 1.0f / (1.0f + expf(v1 - v0));  // v1<=v0, safe
    sel[2 * t] = b0; sel[2 * t + 1] = b1;
    wts[2 * t] = w0; wts[2 * t + 1] = 1.0f - w0;
    atomicAdd(&s_cnt[2 * b0], 1);       // bin = expert*2 + slot
    atomicAdd(&s_cnt[2 * b1 + 1], 1);
  }
  __syncthreads();
  if (tid < NB && s_cnt[tid]) atomicAdd(&cnt[tid], s_cnt[tid]);
}

// ============ scan: padded (x64) exclusive offsets over 16 bins ============
__global__ void k_scan(const int* __restrict__ cnt, int* __restrict__ offs) {
  if (threadIdx.x == 0 && blockIdx.x == 0) {
    int o = 0;
#pragma unroll
    for (int b = 0; b < NB; ++b) { offs[b] = o; o += (cnt[b] + 63) & ~63; }
    offs[NB] = o;
  }
}

// ============ scatter: build (expert,slot)-sorted row lists ============
__global__ __launch_bounds__(256) void k_scatter(const int* __restrict__ sel,
                                                 const float* __restrict__ wts,
                                                 const int* __restrict__ offs,
                                                 int* __restrict__ cursor,
                                                 int* __restrict__ rtok,
                                                 float* __restrict__ rwt) {
  __shared__ int s_cnt[NB], s_base[NB];
  int tid = threadIdx.x;
  if (tid < NB) s_cnt[tid] = 0;
  __syncthreads();
  int g = blockIdx.x * 256 + tid;          // token*2 + slot
  int b = sel[g] * 2 + (g & 1);
  int lpos = atomicAdd(&s_cnt[b], 1);
  __syncthreads();
  if (tid < NB) s_base[tid] = s_cnt[tid] ? atomicAdd(&cursor[tid], s_cnt[tid]) : 0;
  __syncthreads();
  int row = offs[b] + s_base[b] + lpos;
  rtok[row] = g >> 1;
  rwt[row] = wts[g];
}

// ============ GEMM1 + SwiGLU: h[row][256] = silu(x@w1) * (x@w3), bf16 ============
__global__ __launch_bounds__(512, 4) void k_gemm1(const float* __restrict__ x,
                                                  const u16* __restrict__ W13p,
                                                  const int* __restrict__ rtok,
                                                  const int* __restrict__ offs,
                                                  u16* __restrict__ h) {
  __shared__ __align__(16) u16 A_s[64][40];
  __shared__ __align__(16) u16 B_s[512][40];
  int row0 = blockIdx.x * 64;
  if (row0 >= offs[NB]) return;
  int b2 = 0;
  while (row0 >= offs[b2 + 1]) ++b2;
  int e = b2 >> 1;
  int tid = threadIdx.x;
  int ar = tid >> 3, ac = (tid & 7) * 4;
  int tk = rtok[row0 + ar];
  if (tk < 0) tk = 0;                        // pad row: read token 0, output unused
  const float* xrow = x + (size_t)tk * DIM;
  const u16* Bb = W13p + (size_t)e * 512 * 1024;
  int wv = tid >> 6, lane = tid & 63;
  int lr = lane & 15, q = lane >> 4;
  v4f acc[4][4] = {};
  for (int k0 = 0; k0 < DIM; k0 += 32) {
    float4 xv = *(const float4*)(xrow + k0 + ac);
    ushort4 a4;
    a4.x = f2bf(xv.x); a4.y = f2bf(xv.y); a4.z = f2bf(xv.z); a4.w = f2bf(xv.w);
    *(ushort4*)(&A_s[ar][ac]) = a4;
#pragma unroll
    for (int qq = 0; qq < 4; ++qq) {
      int id = qq * 512 + tid;
      int n = id >> 2, c8 = (id & 3) * 8;
      *(uint4*)(&B_s[n][c8]) = *(const uint4*)(Bb + (size_t)n * 1024 + k0 + c8);
    }
    __syncthreads();
    v8s a[4], b[4];
#pragma unroll
    for (int mt = 0; mt < 4; ++mt) a[mt] = *(const v8s*)(&A_s[16 * mt + lr][q * 8]);
#pragma unroll
    for (int nt = 0; nt < 4; ++nt) b[nt] = *(const v8s*)(&B_s[64 * wv + 16 * nt + lr][q * 8]);
#pragma unroll
    for (int mt = 0; mt < 4; ++mt)
#pragma unroll
      for (int nt = 0; nt < 4; ++nt)
        acc[mt][nt] = __builtin_amdgcn_mfma_f32_16x16x32_bf16(a[mt], b[nt], acc[mt][nt], 0, 0, 0);
    __syncthreads();
  }
#pragma unroll
  for (int mt = 0; mt < 4; ++mt)
#pragma unroll
    for (int nt = 0; nt < 2; ++nt)
#pragma unroll
      for (int r = 0; r < 4; ++r) {
        float x1 = bf2f(f2bf(acc[mt][nt][r]));      // match ref bf16 rounding
        float x3 = bf2f(f2bf(acc[mt][nt + 2][r]));
        float hv = x1 * x3 / (1.0f + __expf(-x1));  // silu(x1)*x3
        int row = row0 + 16 * mt + q * 4 + r;
        int col = 32 * wv + 16 * nt + lr;
        h[(size_t)row * DFF + col] = f2bf(hv);
      }
}

// ============ GEMM2: two ordered passes, no atomics ============
// pass 0: slot-0 tiles, plain store (covers every out element)
// pass 1: slot-1 tiles, load-add-store (each element touched once per pass)
__global__ __launch_bounds__(512, 4) void k_gemm2(const u16* __restrict__ h,
                                                  const u16* __restrict__ W2t,
                                                  const int* __restrict__ rtok,
                                                  const float* __restrict__ rwt,
                                                  const int* __restrict__ offs,
                                                  float* __restrict__ out,
                                                  int pass) {
  __shared__ __align__(16) u16 A_s[64][40];
  __shared__ __align__(16) u16 B_s[512][40];
  __shared__ int s_tok[64];
  __shared__ float s_wt[64];
  int row0 = blockIdx.x * 64;
  if (row0 >= offs[NB]) return;
  int b2 = 0;
  while (row0 >= offs[b2 + 1]) ++b2;
  if ((b2 & 1) != pass) return;             // tiles are (expert,slot)-pure
  int e = b2 >> 1;
  int nb = blockIdx.y;
  int tid = threadIdx.x;
  if (tid < 64) { s_tok[tid] = rtok[row0 + tid]; s_wt[tid] = rwt[row0 + tid]; }
  int ar = tid >> 3, ac = (tid & 7) * 4;
  const u16* hrow = h + (size_t)(row0 + ar) * DFF;
  const u16* Bb = W2t + (size_t)e * DIM * DFF + (size_t)nb * 512 * DFF;
  int wv = tid >> 6, lane = tid & 63;
  int lr = lane & 15, q = lane >> 4;
  v4f acc[4][4] = {};
  for (int k0 = 0; k0 < DFF; k0 += 32) {
    *(ushort4*)(&A_s[ar][ac]) = *(const ushort4*)(hrow + k0 + ac);
#pragma unroll
    for (int qq = 0; qq < 4; ++qq) {
      int id = qq * 512 + tid;
      int n = id >> 2, c8 = (id & 3) * 8;
      *(uint4*)(&B_s[n][c8]) = *(const uint4*)(Bb + (size_t)n * DFF + k0 + c8);
    }
    __syncthreads();
    v8s a[4], b[4];
#pragma unroll
    for (int mt = 0; mt < 4; ++mt) a[mt] = *(const v8s*)(&A_s[16 * mt + lr][q * 8]);
#pragma unroll
    for (int nt = 0; nt < 4; ++nt) b[nt] = *(const v8s*)(&B_s[64 * wv + 16 * nt + lr][q * 8]);
#pragma unroll
    for (int mt = 0; mt < 4; ++mt)
#pragma unroll
      for (int nt = 0; nt < 4; ++nt)
        acc[mt][nt] = __builtin_amdgcn_mfma_f32_16x16x32_bf16(a[mt], b[nt], acc[mt][nt], 0, 0, 0);
    __syncthreads();
  }
#pragma unroll
  for (int mt = 0; mt < 4; ++mt)
#pragma unroll
    for (int nt = 0; nt < 4; ++nt) {
      int col = nb * 512 + 64 * wv + 16 * nt + lr;
#pragma unroll
      for (int r = 0; r < 4; ++r) {
        int m = 16 * mt + q * 4 + r;
        int tok = s_tok[m];
        if (tok < 0) continue;               // pad row: no store
        float val = bf2f(f2bf(acc[mt][nt][r])) * s_wt[m];
        float* p = out + (size_t)tok * DIM + col;
        if (pass == 0) *p = val;
        else           *p += val;
      }
    }
}

extern "C" void kernel_launch(void* const* d_in, const int* in_sizes, int n_in,
                              void* d_out, int out_size, void* d_ws, size_t ws_size,
                              hipStream_t stream) {
  (void)in_sizes; (void)n_in; (void)ws_size; (void)out_size;
  const float* x  = (const float*)d_in[0];
  const float* rw = (const float*)d_in[1];
  const float* w1 = (const float*)d_in[2];
  const float* w2 = (const float*)d_in[3];
  const float* w3 = (const float*)d_in[4];
  float* out = (float*)d_out;
  char* ws = (char*)d_ws;
  u16*   W13p = (u16*)(ws + WS_W13);
  u16*   W2t  = (u16*)(ws + WS_W2T);
  u16*   hbuf = (u16*)(ws + WS_H);
  int*   rtok = (int*)(ws + WS_RTOK);
  float* rwt  = (float*)(ws + WS_RWT);
  int*   cnt  = (int*)(ws + WS_CNT);
  int*   cur  = (int*)(ws + WS_CUR);
  int*   offs = (int*)(ws + WS_OFF);
  int*   sel  = (int*)(ws + WS_SEL);
  float* wts  = (float*)(ws + WS_WTS);

  hipMemsetAsync(ws + WS_RTOK, 0xFF, (size_t)MAXROWS * 4, stream);  // rtok = -1 (pad marker)
  hipMemsetAsync(ws + WS_CNT, 0, 128, stream);                      // cnt, cur

  k_pack13<<<dim3(32, 8, 8), dim3(32, 8), 0, stream>>>(w1, w3, W13p);
  k_pack2 <<<dim3(8, 32, 8), dim3(32, 8), 0, stream>>>(w2, W2t);
  k_router<<<dim3(T_TOK / 32), dim3(256), 0, stream>>>(x, rw, sel, wts, cnt);
  k_scan  <<<dim3(1), dim3(64), 0, stream>>>(cnt, offs);
  k_scatter<<<dim3(ROWS / 256), dim3(256), 0, stream>>>(sel, wts, offs, cur, rtok, rwt);
  k_gemm1 <<<dim3(MAXTILES), dim3(512), 0, stream>>>(x, W13p, rtok, offs, hbuf);
  k_gemm2 <<<dim3(MAXTILES, 2), dim3(512), 0, stream>>>(hbuf, W2t, rtok, rwt, offs, out, 0);
  k_gemm2 <<<dim3(MAXTILES, 2), dim3(512), 0, stream>>>(hbuf, W2t, rtok, rwt, offs, out, 1);
}

// Round 5
// 523.004 us; speedup vs baseline: 1.4119x; 1.1508x over previous
//
#include <hip/hip_runtime.h>
#include <cstdint>
#include <cstddef>
#include <math.h>

#define T_TOK 32768
#define DIM   1024
#define DFF   256
#define NE    8
#define NB    16                 // (expert, slot) bins
#define ROWS  (T_TOK * 2)        // 65536 token-expert rows
#define MAXROWS 66560            // ROWS + 16*63 pad, rounded to x64
#define MAXTILES (MAXROWS / 64)  // 1040

typedef unsigned short u16;
typedef __attribute__((ext_vector_type(8))) short v8s;   // 8 bf16 (4 VGPR)
typedef __attribute__((ext_vector_type(4))) float v4f;   // MFMA acc

__device__ __forceinline__ u16 f2bf(float f) {
  union { float f; unsigned u; } v; v.f = f;
  return (u16)((v.u + 0x7FFFu + ((v.u >> 16) & 1u)) >> 16);  // RNE
}
__device__ __forceinline__ float bf2f(u16 b) {
  union { unsigned u; float f; } v; v.u = ((unsigned)b) << 16; return v.f;
}

// ---------------- ws layout (bytes) ----------------
#define WS_W13  ((size_t)0)              // 8*512*1024*2   = 8388608
#define WS_W2T  ((size_t)8388608)        // 8*1024*256*2   = 4194304
#define WS_H    ((size_t)12582912)       // 66560*256*2    = 34078720
#define WS_Y    ((size_t)46661632)       // 66560*1024*2   = 136314880
#define WS_RTOK ((size_t)182976512)      // 66560*4        = 266240
#define WS_POS  ((size_t)183242752)      // 65536*4        = 262144
#define WS_CNT  ((size_t)183504896)      // 16*4 pad 64
#define WS_CUR  ((size_t)183504960)      // 16*4 pad 64
#define WS_OFF  ((size_t)183505024)      // 17*4 pad 128
#define WS_SEL  ((size_t)183505152)      // 65536*4        = 262144
#define WS_WTS  ((size_t)183767296)      // 65536*4  -> total 184029440

// ============ weight packing: w1/w3 -> W13p[e][n=512][k=1024] bf16 ============
__global__ __launch_bounds__(256) void k_pack13(const float* __restrict__ w1,
                                                const float* __restrict__ w3,
                                                u16* __restrict__ W13p) {
  __shared__ float s1[32][33];
  __shared__ float s3[32][33];
  int e = blockIdx.z, k0 = blockIdx.x * 32, j0w = blockIdx.y;
  int tx = threadIdx.x, ty = threadIdx.y;
  size_t wbase = (size_t)e * DIM * DFF;
#pragma unroll
  for (int r = 0; r < 4; ++r) {
    int kl = ty + 8 * r;
    size_t src = wbase + (size_t)(k0 + kl) * DFF + j0w * 32 + tx;
    s1[kl][tx] = w1[src];
    s3[kl][tx] = w3[src];
  }
  __syncthreads();
  size_t obase = (size_t)e * 512 * 1024;
#pragma unroll
  for (int r = 0; r < 4; ++r) {
    int jl = ty + 8 * r;
    int n1 = 64 * j0w + jl;
    W13p[obase + (size_t)n1 * 1024 + k0 + tx]        = f2bf(s1[tx][jl]);
    W13p[obase + (size_t)(n1 + 32) * 1024 + k0 + tx] = f2bf(s3[tx][jl]);
  }
}

// ============ w2 [e][k=256][n=1024] -> W2t[e][n=1024][k=256] bf16 ============
__global__ __launch_bounds__(256) void k_pack2(const float* __restrict__ w2,
                                               u16* __restrict__ W2t) {
  __shared__ float s[32][33];
  int e = blockIdx.z, k0 = blockIdx.x * 32, n0 = blockIdx.y * 32;
  int tx = threadIdx.x, ty = threadIdx.y;
#pragma unroll
  for (int r = 0; r < 4; ++r) {
    int kl = ty + 8 * r;
    s[kl][tx] = w2[(size_t)e * DFF * DIM + (size_t)(k0 + kl) * DIM + n0 + tx];
  }
  __syncthreads();
#pragma unroll
  for (int r = 0; r < 4; ++r) {
    int nl = ty + 8 * r;
    W2t[(size_t)e * DIM * DFF + (size_t)(n0 + nl) * DFF + k0 + tx] = f2bf(s[tx][nl]);
  }
}

// ============ router: np-order fp32 logits, LDS-staged (coalesced) ============
__global__ __launch_bounds__(256) void k_router(const float* __restrict__ x,
                                                const float* __restrict__ rw,
                                                int* __restrict__ sel,
                                                float* __restrict__ wts,
                                                int* __restrict__ cnt) {
  __shared__ __align__(16) float s_rw[NE][1028];
  __shared__ __align__(16) float s_x[32][132];
  __shared__ float s_lg[256];
  __shared__ int s_cnt[NB];
  int tid = threadIdx.x;
  if (tid < NB) s_cnt[tid] = 0;
  {
    const float4* rw4 = (const float4*)rw;
#pragma unroll
    for (int r = 0; r < 8; ++r)
      *(float4*)(&s_rw[r][tid * 4]) = rw4[r * 256 + tid];
  }
  int tl = tid >> 3, e = tid & 7;
  float acc = 0.0f;
  const float4* x4 = (const float4*)x;
  for (int c = 0; c < 8; ++c) {          // 8 chunks of 128 k
    __syncthreads();
#pragma unroll
    for (int j = 0; j < 4; ++j) {
      int slot = j * 256 + tid;
      int t = slot >> 5, kk = (slot & 31) * 4;
      *(float4*)(&s_x[t][kk]) = x4[((size_t)blockIdx.x * 32 + t) * 256 + c * 32 + (slot & 31)];
    }
    __syncthreads();
    const float* xp = &s_x[tl][0];
    const float* wp = &s_rw[e][c * 128];
#pragma unroll 16
    for (int k = 0; k < 128; ++k) acc = fmaf(xp[k], wp[k], acc);  // strict sequential
  }
  s_lg[tid] = acc;
  __syncthreads();
  if ((tid & 7) == 0) {
    int t = blockIdx.x * 32 + tl;
    const float* lg = s_lg + tid;
    int b0 = 0; float v0 = lg[0];
#pragma unroll
    for (int ee = 1; ee < NE; ++ee) if (lg[ee] > v0) { v0 = lg[ee]; b0 = ee; }
    int b1 = -1; float v1 = -1e30f;
#pragma unroll
    for (int ee = 0; ee < NE; ++ee) if (ee != b0 && lg[ee] > v1) { v1 = lg[ee]; b1 = ee; }
    float w0 = 1.0f / (1.0f + expf(v1 - v0));  // v1<=v0, safe
    sel[2 * t] = b0; sel[2 * t + 1] = b1;
    wts[2 * t] = w0; wts[2 * t + 1] = 1.0f - w0;
    atomicAdd(&s_cnt[2 * b0], 1);       // bin = expert*2 + slot
    atomicAdd(&s_cnt[2 * b1 + 1], 1);
  }
  __syncthreads();
  if (tid < NB && s_cnt[tid]) atomicAdd(&cnt[tid], s_cnt[tid]);
}

// ============ scan: padded (x64) exclusive offsets over 16 bins ============
__global__ void k_scan(const int* __restrict__ cnt, int* __restrict__ offs) {
  if (threadIdx.x == 0 && blockIdx.x == 0) {
    int o = 0;
#pragma unroll
    for (int b = 0; b < NB; ++b) { offs[b] = o; o += (cnt[b] + 63) & ~63; }
    offs[NB] = o;
  }
}

// ============ scatter: build (expert,slot)-sorted row lists + pos map ============
__global__ __launch_bounds__(256) void k_scatter(const int* __restrict__ sel,
                                                 const int* __restrict__ offs,
                                                 int* __restrict__ cursor,
                                                 int* __restrict__ rtok,
                                                 int* __restrict__ pos) {
  __shared__ int s_cnt[NB], s_base[NB];
  int tid = threadIdx.x;
  if (tid < NB) s_cnt[tid] = 0;
  __syncthreads();
  int g = blockIdx.x * 256 + tid;          // token*2 + slot
  int b = sel[g] * 2 + (g & 1);
  int lpos = atomicAdd(&s_cnt[b], 1);
  __syncthreads();
  if (tid < NB) s_base[tid] = s_cnt[tid] ? atomicAdd(&cursor[tid], s_cnt[tid]) : 0;
  __syncthreads();
  int row = offs[b] + s_base[b] + lpos;
  rtok[row] = g >> 1;
  pos[g] = row;
}

// ============ GEMM1 + SwiGLU: h[row][256] = silu(x@w1) * (x@w3), bf16 ============
__global__ __launch_bounds__(512, 4) void k_gemm1(const float* __restrict__ x,
                                                  const u16* __restrict__ W13p,
                                                  const int* __restrict__ rtok,
                                                  const int* __restrict__ offs,
                                                  u16* __restrict__ h) {
  __shared__ __align__(16) u16 A_s[64][40];
  __shared__ __align__(16) u16 B_s[512][40];
  int row0 = blockIdx.x * 64;
  if (row0 >= offs[NB]) return;
  int b2 = 0;
  while (row0 >= offs[b2 + 1]) ++b2;
  int e = b2 >> 1;
  int tid = threadIdx.x;
  int ar = tid >> 3, ac = (tid & 7) * 4;
  int tk = rtok[row0 + ar];
  if (tk < 0) tk = 0;                        // pad row: read token 0, output unused
  const float* xrow = x + (size_t)tk * DIM;
  const u16* Bb = W13p + (size_t)e * 512 * 1024;
  int wv = tid >> 6, lane = tid & 63;
  int lr = lane & 15, q = lane >> 4;
  v4f acc[4][4] = {};
  for (int k0 = 0; k0 < DIM; k0 += 32) {
    float4 xv = *(const float4*)(xrow + k0 + ac);
    ushort4 a4;
    a4.x = f2bf(xv.x); a4.y = f2bf(xv.y); a4.z = f2bf(xv.z); a4.w = f2bf(xv.w);
    *(ushort4*)(&A_s[ar][ac]) = a4;
#pragma unroll
    for (int qq = 0; qq < 4; ++qq) {
      int id = qq * 512 + tid;
      int n = id >> 2, c8 = (id & 3) * 8;
      *(uint4*)(&B_s[n][c8]) = *(const uint4*)(Bb + (size_t)n * 1024 + k0 + c8);
    }
    __syncthreads();
    v8s a[4], b[4];
#pragma unroll
    for (int mt = 0; mt < 4; ++mt) a[mt] = *(const v8s*)(&A_s[16 * mt + lr][q * 8]);
#pragma unroll
    for (int nt = 0; nt < 4; ++nt) b[nt] = *(const v8s*)(&B_s[64 * wv + 16 * nt + lr][q * 8]);
#pragma unroll
    for (int mt = 0; mt < 4; ++mt)
#pragma unroll
      for (int nt = 0; nt < 4; ++nt)
        acc[mt][nt] = __builtin_amdgcn_mfma_f32_16x16x32_bf16(a[mt], b[nt], acc[mt][nt], 0, 0, 0);
    __syncthreads();
  }
#pragma unroll
  for (int mt = 0; mt < 4; ++mt)
#pragma unroll
    for (int nt = 0; nt < 2; ++nt)
#pragma unroll
      for (int r = 0; r < 4; ++r) {
        float x1 = bf2f(f2bf(acc[mt][nt][r]));      // match ref bf16 rounding
        float x3 = bf2f(f2bf(acc[mt][nt + 2][r]));
        float hv = x1 * x3 / (1.0f + __expf(-x1));  // silu(x1)*x3
        int row = row0 + 16 * mt + q * 4 + r;
        int col = 32 * wv + 16 * nt + lr;
        h[(size_t)row * DFF + col] = f2bf(hv);
      }
}

// ============ GEMM2: y[row][1024] bf16, row-ordered coalesced stores ============
// Epilogue transposes each 16-row slab through LDS (reusing B_s) so global
// stores are contiguous uint4. No token scatter, no RMW, single pass.
__global__ __launch_bounds__(512, 4) void k_gemm2(const u16* __restrict__ h,
                                                  const u16* __restrict__ W2t,
                                                  const int* __restrict__ offs,
                                                  u16* __restrict__ y) {
  __shared__ __align__(16) u16 A_s[64][40];
  __shared__ __align__(16) u16 B_s[512][40];  // reused as T[16][520] in epilogue
  int row0 = blockIdx.x * 64;
  if (row0 >= offs[NB]) return;
  int b2 = 0;
  while (row0 >= offs[b2 + 1]) ++b2;
  int e = b2 >> 1;
  int nb = blockIdx.y;
  int tid = threadIdx.x;
  int ar = tid >> 3, ac = (tid & 7) * 4;
  const u16* hrow = h + (size_t)(row0 + ar) * DFF;
  const u16* Bb = W2t + (size_t)e * DIM * DFF + (size_t)nb * 512 * DFF;
  int wv = tid >> 6, lane = tid & 63;
  int lr = lane & 15, q = lane >> 4;
  v4f acc[4][4] = {};
  for (int k0 = 0; k0 < DFF; k0 += 32) {
    *(ushort4*)(&A_s[ar][ac]) = *(const ushort4*)(hrow + k0 + ac);
#pragma unroll
    for (int qq = 0; qq < 4; ++qq) {
      int id = qq * 512 + tid;
      int n = id >> 2, c8 = (id & 3) * 8;
      *(uint4*)(&B_s[n][c8]) = *(const uint4*)(Bb + (size_t)n * DFF + k0 + c8);
    }
    __syncthreads();
    v8s a[4], b[4];
#pragma unroll
    for (int mt = 0; mt < 4; ++mt) a[mt] = *(const v8s*)(&A_s[16 * mt + lr][q * 8]);
#pragma unroll
    for (int nt = 0; nt < 4; ++nt) b[nt] = *(const v8s*)(&B_s[64 * wv + 16 * nt + lr][q * 8]);
#pragma unroll
    for (int mt = 0; mt < 4; ++mt)
#pragma unroll
      for (int nt = 0; nt < 4; ++nt)
        acc[mt][nt] = __builtin_amdgcn_mfma_f32_16x16x32_bf16(a[mt], b[nt], acc[mt][nt], 0, 0, 0);
    __syncthreads();
  }
  // epilogue: per 16-row slab (mt), LDS transpose -> coalesced uint4 stores
  u16* Ts = &B_s[0][0];                      // viewed as [16][520]
#pragma unroll
  for (int mt = 0; mt < 4; ++mt) {
#pragma unroll
    for (int nt = 0; nt < 4; ++nt)
#pragma unroll
      for (int r = 0; r < 4; ++r)
        Ts[(q * 4 + r) * 520 + 64 * wv + 16 * nt + lr] = f2bf(acc[mt][nt][r]);
    __syncthreads();
#pragma unroll
    for (int i = 0; i < 2; ++i) {
      int j = tid + 512 * i;                 // 1024 uint4 slots = 16 rows x 64
      int rr = j >> 6, cc = j & 63;
      uint4 v = *(const uint4*)(Ts + rr * 520 + cc * 8);
      *(uint4*)(y + (size_t)(row0 + 16 * mt + rr) * 1024 + nb * 512 + cc * 8) = v;
    }
    __syncthreads();
  }
}

// ============ combine: out[t] = w0*fp32(y[pos0]) + w1*fp32(y[pos1]) ============
__global__ __launch_bounds__(256) void k_combine(const u16* __restrict__ y,
                                                 const int* __restrict__ pos,
                                                 const float* __restrict__ wts,
                                                 float* __restrict__ out) {
  int tid = threadIdx.x, wv = tid >> 6, lane = tid & 63;
  int t = blockIdx.x * 4 + wv;
  int r0 = pos[2 * t], r1 = pos[2 * t + 1];
  float w0 = wts[2 * t], w1 = wts[2 * t + 1];
  const uint4* y0 = (const uint4*)(y + (size_t)r0 * 1024);
  const uint4* y1 = (const uint4*)(y + (size_t)r1 * 1024);
  float* o = out + (size_t)t * 1024;
#pragma unroll
  for (int i = 0; i < 2; ++i) {
    int j = lane + 64 * i;                   // 128 uint4 per row
    uint4 a = y0[j], b = y1[j];
    const u16* pa = (const u16*)&a;
    const u16* pb = (const u16*)&b;
    float f[8];
#pragma unroll
    for (int k = 0; k < 8; ++k) f[k] = bf2f(pa[k]) * w0 + bf2f(pb[k]) * w1;
    *(float4*)(o + j * 8)     = *(float4*)&f[0];
    *(float4*)(o + j * 8 + 4) = *(float4*)&f[4];
  }
}

extern "C" void kernel_launch(void* const* d_in, const int* in_sizes, int n_in,
                              void* d_out, int out_size, void* d_ws, size_t ws_size,
                              hipStream_t stream) {
  (void)in_sizes; (void)n_in; (void)ws_size; (void)out_size;
  const float* x  = (const float*)d_in[0];
  const float* rw = (const float*)d_in[1];
  const float* w1 = (const float*)d_in[2];
  const float* w2 = (const float*)d_in[3];
  const float* w3 = (const float*)d_in[4];
  float* out = (float*)d_out;
  char* ws = (char*)d_ws;
  u16*   W13p = (u16*)(ws + WS_W13);
  u16*   W2t  = (u16*)(ws + WS_W2T);
  u16*   hbuf = (u16*)(ws + WS_H);
  u16*   ybuf = (u16*)(ws + WS_Y);
  int*   rtok = (int*)(ws + WS_RTOK);
  int*   pos  = (int*)(ws + WS_POS);
  int*   cnt  = (int*)(ws + WS_CNT);
  int*   cur  = (int*)(ws + WS_CUR);
  int*   offs = (int*)(ws + WS_OFF);
  int*   sel  = (int*)(ws + WS_SEL);
  float* wts  = (float*)(ws + WS_WTS);

  hipMemsetAsync(ws + WS_RTOK, 0xFF, (size_t)MAXROWS * 4, stream);  // rtok = -1 (pad marker)
  hipMemsetAsync(ws + WS_CNT, 0, 128, stream);                      // cnt, cur

  k_pack13<<<dim3(32, 8, 8), dim3(32, 8), 0, stream>>>(w1, w3, W13p);
  k_pack2 <<<dim3(8, 32, 8), dim3(32, 8), 0, stream>>>(w2, W2t);
  k_router<<<dim3(T_TOK / 32), dim3(256), 0, stream>>>(x, rw, sel, wts, cnt);
  k_scan  <<<dim3(1), dim3(64), 0, stream>>>(cnt, offs);
  k_scatter<<<dim3(ROWS / 256), dim3(256), 0, stream>>>(sel, offs, cur, rtok, pos);
  k_gemm1 <<<dim3(MAXTILES), dim3(512), 0, stream>>>(x, W13p, rtok, offs, hbuf);
  k_gemm2 <<<dim3(MAXTILES, 2), dim3(512), 0, stream>>>(hbuf, W2t, offs, ybuf);
  k_combine<<<dim3(T_TOK / 4), dim3(256), 0, stream>>>(ybuf, pos, wts, out);
}